// Round 10
// baseline (157.027 us; speedup 1.0000x reference)
//
#include <hip/hip_runtime.h>
#include <hip/hip_bf16.h>
#include <math.h>

typedef __attribute__((ext_vector_type(8))) short short8;
typedef __attribute__((ext_vector_type(4))) short s16x4;
typedef __attribute__((ext_vector_type(4))) float f32x4;

#define BB 4
#define HW 4096
#define CC 256
#define FC 64
#define L2E 1.4426950408889634f

// ws byte offsets
#define OFF_EMB   0                      // short[16384*64]   = 2 MB
#define OFF_SCT2  (2*1024*1024)          // short[4*64*8*256*8] = 8 MB
#define OFF_SQN   (OFF_SCT2 + 8*1024*1024)
#define OFF_T     (OFF_SQN + 65536)
#define OFF_D     (OFF_T   + 65536)
#define OFF_WEMB2 (OFF_D   + 65536)      // short[32*64*8] = 32 KB
#define OFF_WATT2 (OFF_WEMB2 + 32768)    // short[32*256*8] = 128 KB
#define OFF_EXPA  (16*1024*1024)         // bf16[4][4096][4096] = 128 MB
#define EXPA_BYTES ((size_t)BB*HW*HW*2)
#define WS_NEED   ((size_t)OFF_EXPA + EXPA_BYTES)

static __device__ __forceinline__ short f2bf(float f) {
    __hip_bfloat16 h = __float2bfloat16(f);
    return *reinterpret_cast<short*>(&h);
}
static __device__ __forceinline__ float bf2f(short s) {
    __hip_bfloat16 h = *reinterpret_cast<__hip_bfloat16*>(&s);
    return __bfloat162float(h);
}
static __device__ __forceinline__ float fexp2(float x) {
#if __has_builtin(__builtin_amdgcn_exp2f)
    return __builtin_amdgcn_exp2f(x);
#else
    float r; asm("v_exp_f32 %0, %1" : "=v"(r) : "v"(x)); return r;
#endif
}
static __device__ __forceinline__ float frcp(float x) {
#if __has_builtin(__builtin_amdgcn_rcpf)
    return __builtin_amdgcn_rcpf(x);
#else
    return 1.0f / x;
#endif
}
#define MFMA32(a, b, c) __builtin_amdgcn_mfma_f32_16x16x32_bf16(a, b, c, 0, 0, 0)

// ---------------------------------------------------------------------------
// K0: weight conversion to tiled bf16 B-fragment layouts + D zero.
// ---------------------------------------------------------------------------
__global__ __launch_bounds__(256) void k_prep(const float* __restrict__ Wemb,
    const float* __restrict__ Watt, short* __restrict__ Wemb2,
    short* __restrict__ Watt2, float* __restrict__ D)
{
    const int bid = blockIdx.x, t = threadIdx.x;
    if (bid < 256) {
        Watt2[(size_t)(t>>3)*2048 + bid*8 + (t&7)] = f2bf(Watt[(size_t)bid*256 + t]);
        if (bid < 64) D[bid*256 + t] = 0.f;
    } else {
        const int f = bid - 256;
        Wemb2[(size_t)(t>>3)*512 + f*8 + (t&7)] = f2bf(Wemb[(size_t)f*256 + t]);
    }
}

// ---------------------------------------------------------------------------
// K1 (fused emb + shortcut + threshold, all MFMA). grid 1024 x 256.
// ---------------------------------------------------------------------------
__global__ __launch_bounds__(256) void k_front(const float* __restrict__ fm,
    const short* __restrict__ Wemb2, const short* __restrict__ Watt2,
    const float* __restrict__ bemb, const float* __restrict__ batt,
    const float* __restrict__ wthr, const float* __restrict__ bthr,
    short* __restrict__ emb, short* __restrict__ sct2,
    float* __restrict__ sqn, float* __restrict__ T)
{
    const int blk = blockIdx.x;
    const int b = blk >> 8;
    const int r0 = (blk & 255) * 16;
    const int t = threadIdx.x;
    const int w = t >> 6, lane = t & 63, g = lane >> 4, n16 = lane & 15;
    __shared__ short fmt[16*256];
    __shared__ float tred[16][4];
    __shared__ float qred[16][4];
    #pragma unroll
    for (int v = t; v < 512; v += 256) {
        const int row = v >> 5, c32 = v & 31;
        const float4* src = (const float4*)(fm + ((size_t)b*HW + r0 + row)*CC + c32*8);
        float4 x0 = src[0], x1 = src[1];
        short8 pv;
        pv[0]=f2bf(x0.x); pv[1]=f2bf(x0.y); pv[2]=f2bf(x0.z); pv[3]=f2bf(x0.w);
        pv[4]=f2bf(x1.x); pv[5]=f2bf(x1.y); pv[6]=f2bf(x1.z); pv[7]=f2bf(x1.w);
        *(short8*)((char*)fmt + row*512 + ((c32*16) ^ ((row&7)<<4))) = pv;
    }
    __syncthreads();
    const int cb = w*64, fb = w*16;
    f32x4 acc[4], acce;
    #pragma unroll
    for (int nn = 0; nn < 4; ++nn) acc[nn] = (f32x4){0.f,0.f,0.f,0.f};
    acce = (f32x4){0.f,0.f,0.f,0.f};
    #pragma unroll
    for (int kk = 0; kk < 8; ++kk) {
        const int kc = kk*4 + g;
        short8 a = *(const short8*)((const char*)fmt + n16*512 + ((kc*16) ^ ((n16&7)<<4)));
        const short* wb = Watt2 + (size_t)kc*2048 + (cb + n16)*8;
        #pragma unroll
        for (int nn = 0; nn < 4; ++nn) {
            short8 bv = *(const short8*)(wb + nn*128);
            acc[nn] = MFMA32(a, bv, acc[nn]);
        }
        short8 be = *(const short8*)(Wemb2 + (size_t)kc*512 + (fb + n16)*8);
        acce = MFMA32(a, be, acce);
    }
    float tp[4] = {0.f,0.f,0.f,0.f};
    const int jt_ = r0 >> 6;
    const int jc0 = (r0 & 63) >> 3;
    const size_t tilebase = ((size_t)b*64 + jt_)*8;
    #pragma unroll
    for (int nn = 0; nn < 4; ++nn) {
        const int ch = cb + nn*16 + n16;
        const float ba_ = batt[ch], wt_ = wthr[ch];
        float v[4];
        #pragma unroll
        for (int r = 0; r < 4; ++r) { v[r] = acc[nn][r] + ba_; tp[r] = fmaf(v[r], wt_, tp[r]); }
        const int jc = jc0 + (g >> 1);
        const int jw0 = (g & 1)*4;
        short* dstp = sct2 + (tilebase + jc)*2048 + (size_t)ch*8;
        unsigned u01 = (unsigned short)f2bf(v[0]) | ((unsigned)(unsigned short)f2bf(v[1]) << 16);
        unsigned u23 = (unsigned short)f2bf(v[2]) | ((unsigned)(unsigned short)f2bf(v[3]) << 16);
        *(unsigned*)(dstp + jw0)     = u01;
        *(unsigned*)(dstp + jw0 + 2) = u23;
    }
    #pragma unroll
    for (int r = 0; r < 4; ++r)
        #pragma unroll
        for (int off = 1; off <= 8; off <<= 1) tp[r] += __shfl_xor(tp[r], off);
    const int f = fb + n16;
    const float be_ = bemb[f];
    float qp[4];
    #pragma unroll
    for (int r = 0; r < 4; ++r) {
        short bv = f2bf(acce[r] + be_);
        emb[((size_t)b*HW + r0 + g*4 + r)*FC + f] = bv;
        float ef = bf2f(bv);
        qp[r] = ef*ef;
        #pragma unroll
        for (int off = 1; off <= 8; off <<= 1) qp[r] += __shfl_xor(qp[r], off);
    }
    if (n16 == 0) {
        #pragma unroll
        for (int r = 0; r < 4; ++r) { tred[g*4+r][w] = tp[r]; qred[g*4+r][w] = qp[r]; }
    }
    __syncthreads();
    if (t < 16) {
        T[(size_t)b*HW + r0 + t]   = tred[t][0]+tred[t][1]+tred[t][2]+tred[t][3] + bthr[0];
        sqn[(size_t)b*HW + r0 + t] = qred[t][0]+qred[t][1]+qred[t][2]+qred[t][3];
    }
}

// ---------------------------------------------------------------------------
// K2w: column sums D[j] + write unnormalized expA (bf16, [b][i][j] row-major).
// Swapped MFMA operands: lane col = i = n16, row = j = w*16+g*4+r -> 8B stores.
// grid 2048 x 256. 1 barrier/iter, dbuf ei (structure proven in k_colsum).
// ---------------------------------------------------------------------------
__global__ __launch_bounds__(256) void k_colsum_w(const short* __restrict__ emb,
    const float* __restrict__ sqn, const float* __restrict__ T,
    float* __restrict__ D, short* __restrict__ expA)
{
    const int bid = blockIdx.x;
    const int split = bid & 7, jt = (bid >> 3) & 63, b = bid >> 9;
    const int t = threadIdx.x, w = t >> 6, lane = t & 63, g = lane >> 4, n16 = lane & 15;
    const size_t jbase = (size_t)b*HW + jt*64;
    __shared__ short ej[64*64];
    __shared__ short ei[2][64*64];
    __shared__ float sqni[2][64];
    #pragma unroll
    for (int v = t; v < 512; v += 256) {
        const int row = v >> 3, c8 = v & 7;
        short8 x = *(const short8*)(emb + (jbase + row)*FC + c8*8);
        *(short8*)((char*)ej + row*128 + ((c8*16) ^ ((row&7)<<4))) = x;
    }
    const int jl = w*16 + n16;
    // per-lane j-quad scalars (j = w*16 + g*4 + r)
    f32x4 sqjL, tjL;
    {
        f32x4 q = *(const f32x4*)(sqn + jbase + w*16 + g*4);
        f32x4 tt = *(const f32x4*)(T + jbase + w*16 + g*4);
        #pragma unroll
        for (int r = 0; r < 4; ++r) { sqjL[r] = -L2E*q[r]; tjL[r] = -L2E*tt[r]; }
    }
    const int srow0 = t >> 3, srow1 = (t >> 3) + 32, sc8 = t & 7;
    const int sb0 = srow0*128 + ((sc8*16) ^ ((srow0&7)<<4));
    const int sb1 = srow1*128 + ((sc8*16) ^ ((srow1&7)<<4));
    const size_t base0 = (size_t)b*HW + (size_t)split*512;   // global row base
    const int il0 = split*512;                                // i local to batch
    short8 stg0 = *(const short8*)(emb + (base0 + srow0)*FC + sc8*8);
    short8 stg1 = *(const short8*)(emb + (base0 + srow1)*FC + sc8*8);
    float stgq = (t < 64) ? sqn[base0 + t] : 0.f;
    *(short8*)((char*)ei[0] + sb0) = stg0;
    *(short8*)((char*)ei[0] + sb1) = stg1;
    if (t < 64) sqni[0][t] = stgq;
    stg0 = *(const short8*)(emb + (base0 + 64 + srow0)*FC + sc8*8);
    stg1 = *(const short8*)(emb + (base0 + 64 + srow1)*FC + sc8*8);
    stgq = (t < 64) ? sqn[base0 + 64 + t] : 0.f;
    __syncthreads();
    const short8 bf0 = *(const short8*)((const char*)ej + jl*128 + ((g*16)     ^ ((jl&7)<<4)));
    const short8 bf1 = *(const short8*)((const char*)ej + jl*128 + (((g+4)*16) ^ ((jl&7)<<4)));
    f32x4 csum = {0.f,0.f,0.f,0.f};
    // expA store base: row (b*HW + il)*HW + col
    short* expAb = expA + (size_t)b*HW*HW;
    const int jcol = jt*64 + w*16 + g*4;
    for (int it = 0; it < 8; ++it) {
        if (it < 7) {
            char* eib = (char*)ei[(it+1)&1];
            *(short8*)(eib + sb0) = stg0;
            *(short8*)(eib + sb1) = stg1;
            if (t < 64) sqni[(it+1)&1][t] = stgq;
            if (it < 6) {
                const size_t nb = base0 + (size_t)(it+2)*64;
                stg0 = *(const short8*)(emb + (nb + srow0)*FC + sc8*8);
                stg1 = *(const short8*)(emb + (nb + srow1)*FC + sc8*8);
                stgq = (t < 64) ? sqn[nb + t] : 0.f;
            }
        }
        const char* eib = (const char*)ei[it&1];
        const float* sqc = sqni[it&1];
        #pragma unroll
        for (int m = 0; m < 4; ++m) {
            const int arow = m*16 + n16;
            short8 a0 = *(const short8*)(eib + arow*128 + ((g*16)     ^ ((arow&7)<<4)));
            short8 a1 = *(const short8*)(eib + arow*128 + (((g+4)*16) ^ ((arow&7)<<4)));
            f32x4 dot = {0.f,0.f,0.f,0.f};
            dot = MFMA32(bf0, a0, dot);   // swapped: lane col = i = n16
            dot = MFMA32(bf1, a1, dot);
            const float sniL = -L2E * sqc[m*16 + n16];
            s16x4 pk;
            #pragma unroll
            for (int r = 0; r < 4; ++r) {
                float x1 = fminf(fmaf(dot[r], 2.f*L2E, sniL + sqjL[r]), 0.f);
                float a_ = fmaxf(fmaf(fexp2(x1), L2E, tjL[r]), 0.f);
                float val = fexp2(a_);
                csum[r] += val;
                pk[r] = f2bf(val);
            }
            const int il = il0 + it*64 + m*16 + n16;
            *(s16x4*)(expAb + (size_t)il*HW + jcol) = pk;
        }
        __syncthreads();
    }
    #pragma unroll
    for (int r = 0; r < 4; ++r) {
        csum[r] += __shfl_xor(csum[r], 1);
        csum[r] += __shfl_xor(csum[r], 2);
        csum[r] += __shfl_xor(csum[r], 4);
        csum[r] += __shfl_xor(csum[r], 8);
    }
    if (n16 == 0) {
        #pragma unroll
        for (int r = 0; r < 4; ++r) atomicAdd(&D[jbase + w*16 + g*4 + r], csum[r]);
    }
}

// ---------------------------------------------------------------------------
// K2 fallback: column sums only (no expA). grid 2048 x 256.
// ---------------------------------------------------------------------------
__global__ __launch_bounds__(256) void k_colsum(const short* __restrict__ emb,
    const float* __restrict__ sqn, const float* __restrict__ T,
    float* __restrict__ D)
{
    const int bid = blockIdx.x;
    const int split = bid & 7, jt = (bid >> 3) & 63, b = bid >> 9;
    const int t = threadIdx.x, w = t >> 6, lane = t & 63, g = lane >> 4, n16 = lane & 15;
    const size_t jbase = (size_t)b*HW + jt*64;
    __shared__ short ej[64*64];
    __shared__ short ei[2][64*64];
    __shared__ float sqni[2][64];
    #pragma unroll
    for (int v = t; v < 512; v += 256) {
        const int row = v >> 3, c8 = v & 7;
        short8 x = *(const short8*)(emb + (jbase + row)*FC + c8*8);
        *(short8*)((char*)ej + row*128 + ((c8*16) ^ ((row&7)<<4))) = x;
    }
    const int jl = w*16 + n16;
    const float sqjL = -L2E * sqn[jbase + jl];
    const float tjL  = -L2E * T[jbase + jl];
    const int srow0 = t >> 3, srow1 = (t >> 3) + 32, sc8 = t & 7;
    const int sb0 = srow0*128 + ((sc8*16) ^ ((srow0&7)<<4));
    const int sb1 = srow1*128 + ((sc8*16) ^ ((srow1&7)<<4));
    const size_t base0 = (size_t)b*HW + (size_t)split*512;
    short8 stg0 = *(const short8*)(emb + (base0 + srow0)*FC + sc8*8);
    short8 stg1 = *(const short8*)(emb + (base0 + srow1)*FC + sc8*8);
    float stgq = (t < 64) ? sqn[base0 + t] : 0.f;
    *(short8*)((char*)ei[0] + sb0) = stg0;
    *(short8*)((char*)ei[0] + sb1) = stg1;
    if (t < 64) sqni[0][t] = stgq;
    stg0 = *(const short8*)(emb + (base0 + 64 + srow0)*FC + sc8*8);
    stg1 = *(const short8*)(emb + (base0 + 64 + srow1)*FC + sc8*8);
    stgq = (t < 64) ? sqn[base0 + 64 + t] : 0.f;
    __syncthreads();
    const short8 bf0 = *(const short8*)((const char*)ej + jl*128 + ((g*16)     ^ ((jl&7)<<4)));
    const short8 bf1 = *(const short8*)((const char*)ej + jl*128 + (((g+4)*16) ^ ((jl&7)<<4)));
    float csum = 0.f;
    for (int it = 0; it < 8; ++it) {
        if (it < 7) {
            char* eib = (char*)ei[(it+1)&1];
            *(short8*)(eib + sb0) = stg0;
            *(short8*)(eib + sb1) = stg1;
            if (t < 64) sqni[(it+1)&1][t] = stgq;
            if (it < 6) {
                const size_t nb = base0 + (size_t)(it+2)*64;
                stg0 = *(const short8*)(emb + (nb + srow0)*FC + sc8*8);
                stg1 = *(const short8*)(emb + (nb + srow1)*FC + sc8*8);
                stgq = (t < 64) ? sqn[nb + t] : 0.f;
            }
        }
        const char* eib = (const char*)ei[it&1];
        const float* sqc = sqni[it&1];
        #pragma unroll
        for (int m = 0; m < 4; ++m) {
            const int arow = m*16 + n16;
            short8 a0 = *(const short8*)(eib + arow*128 + ((g*16)     ^ ((arow&7)<<4)));
            short8 a1 = *(const short8*)(eib + arow*128 + (((g+4)*16) ^ ((arow&7)<<4)));
            f32x4 dot = {0.f,0.f,0.f,0.f};
            dot = MFMA32(a0, bf0, dot);
            dot = MFMA32(a1, bf1, dot);
            #pragma unroll
            for (int r = 0; r < 4; ++r) {
                float x1 = fminf(fmaf(dot[r], 2.f*L2E, fmaf(-L2E, sqc[m*16 + g*4 + r], sqjL)), 0.f);
                float e1 = fexp2(x1);
                float a_ = fmaxf(fmaf(e1, L2E, tjL), 0.f);
                csum += fexp2(a_);
            }
        }
        __syncthreads();
    }
    csum += __shfl_xor(csum, 16);
    csum += __shfl_xor(csum, 32);
    if (lane < 16) atomicAdd(&D[jbase + jl], csum);
}

// ---------------------------------------------------------------------------
// K3s: fold 1/D[j] into sct2 (in place). grid 2048 x 256, 1 short8/thread.
// ---------------------------------------------------------------------------
__global__ __launch_bounds__(256) void k_scale(short* __restrict__ sct2,
    const float* __restrict__ D)
{
    const int v = blockIdx.x*256 + threadIdx.x;
    const int ch = v & 255, jc = (v >> 8) & 7, jt = (v >> 11) & 63, b = v >> 17;
    const size_t jb = (size_t)b*HW + jt*64 + jc*8;
    f32x4 d0 = *(const f32x4*)(D + jb);
    f32x4 d1 = *(const f32x4*)(D + jb + 4);
    short8* p = (short8*)(sct2 + ((((size_t)b*64 + jt)*8 + jc)*256 + ch)*8);
    short8 x = *p;
    short8 y;
    y[0] = f2bf(bf2f(x[0]) * frcp(d0[0]));
    y[1] = f2bf(bf2f(x[1]) * frcp(d0[1]));
    y[2] = f2bf(bf2f(x[2]) * frcp(d0[2]));
    y[3] = f2bf(bf2f(x[3]) * frcp(d0[3]));
    y[4] = f2bf(bf2f(x[4]) * frcp(d1[0]));
    y[5] = f2bf(bf2f(x[5]) * frcp(d1[1]));
    y[6] = f2bf(bf2f(x[6]) * frcp(d1[2]));
    y[7] = f2bf(bf2f(x[7]) * frcp(d1[3]));
    *p = y;
}

// ---------------------------------------------------------------------------
// K4g: pure GEMM  out = fm + expA @ sc'.  grid 512 x 256 (4 waves), 32 rows,
// ZERO LDS, ZERO barriers. Register double-buffered A/B frags from L2/L3.
// wave w: channels w*64..+63 x all 32 rows. 16 MFMA/tile.
// ---------------------------------------------------------------------------
#define LDA(DST, JT) { _Pragma("unroll") for (int m = 0; m < 2; ++m) {       \
        const short* p_ = Arow + (size_t)(m*16)*HW + (JT)*64;                \
        (DST)[m*2+0] = *(const short8*)(p_);                                 \
        (DST)[m*2+1] = *(const short8*)(p_ + 32); } }
#define LDB(DST, JT) { const short* q_ = Bbase + (size_t)(JT)*16384;         \
        _Pragma("unroll") for (int nn = 0; nn < 4; ++nn)                     \
        _Pragma("unroll") for (int kc = 0; kc < 2; ++kc)                     \
        (DST)[nn*2+kc] = *(const short8*)(q_ + (kc*4+g)*2048 + nn*128); }
#define GTILE(AV, BV) { _Pragma("unroll") for (int m = 0; m < 2; ++m)        \
        _Pragma("unroll") for (int nn = 0; nn < 4; ++nn) {                   \
        acc[m][nn] = MFMA32((AV)[m*2+0], (BV)[nn*2+0], acc[m][nn]);          \
        acc[m][nn] = MFMA32((AV)[m*2+1], (BV)[nn*2+1], acc[m][nn]); } }

__global__ __launch_bounds__(256) void k_attn_g(const float* __restrict__ fm,
    const short* __restrict__ expA, const short* __restrict__ sct2,
    float* __restrict__ out)
{
    const int bid = ((blockIdx.x & 7) << 6) | (blockIdx.x >> 3);  // 512 blocks
    const int b = bid >> 7;
    const int i0 = (bid & 127) * 32;
    const int t = threadIdx.x, w = t >> 6, lane = t & 63, g = lane >> 4, n16 = lane & 15;
    const short* Arow  = expA + ((size_t)b*HW + i0 + n16)*HW + g*8;
    const short* Bbase = sct2 + (size_t)(b*64)*8*2048 + (size_t)(w*64 + n16)*8;

    short8 aA[4], aB[4], bA[8], bB[8];
    f32x4 acc[2][4];
    #pragma unroll
    for (int m = 0; m < 2; ++m)
        #pragma unroll
        for (int nn = 0; nn < 4; ++nn) acc[m][nn] = (f32x4){0.f,0.f,0.f,0.f};

    LDA(aA, 0)
    LDB(bA, 0)
    for (int jt = 0; jt < 64; jt += 2) {
        LDA(aB, jt+1)
        LDB(bB, jt+1)
        GTILE(aA, bA)
        const int j2 = (jt+2 < 64) ? jt+2 : 63;
        LDA(aA, j2)
        LDB(bA, j2)
        GTILE(aB, bB)
    }

    const size_t ibase = (size_t)b*HW + i0;
    #pragma unroll
    for (int m = 0; m < 2; ++m)
        #pragma unroll
        for (int r = 0; r < 4; ++r) {
            const size_t row = ibase + m*16 + g*4 + r;
            #pragma unroll
            for (int nn = 0; nn < 4; ++nn) {
                const size_t idx = row*CC + w*64 + nn*16 + n16;
                out[idx] = fm[idx] + acc[m][nn][r];
            }
        }
}

// ---------------------------------------------------------------------------
// K4 fallback (R9): fused score + normalize + PV, double-width windows.
// ---------------------------------------------------------------------------
#define SCORE_XF(TT, EJB, PW, SQ, TJ, DD)                                      \
  {                                                                            \
    const char* ejb_ = (EJB) + (TT)*8192;                                      \
    short8 b0 = *(const short8*)(ejb_ + jl*128 + ((g*16)     ^ ((jl&7)<<4)));  \
    short8 b1 = *(const short8*)(ejb_ + jl*128 + (((g+4)*16) ^ ((jl&7)<<4)));  \
    const float iD   = frcp(DD);                                               \
    const float sqjL = -L2E * (SQ);                                            \
    const float tjL  = -L2E * (TJ);                                            \
    _Pragma("unroll")                                                          \
    for (int t2 = 0; t2 < 2; ++t2) {                                           \
      f32x4 dot = {0.f,0.f,0.f,0.f};                                           \
      dot = MFMA32(aQ0[t2], b0, dot);                                          \
      dot = MFMA32(aQ1[t2], b1, dot);                                          \
      _Pragma("unroll")                                                        \
      for (int r = 0; r < 4; ++r) {                                            \
        float x1 = fminf(fmaf(dot[r], 2.f*L2E, snL[t2][r] + sqjL), 0.f);       \
        float a_ = fmaxf(fmaf(fexp2(x1), L2E, tjL), 0.f);                      \
        const int prow = ih*32 + t2*16 + g*4 + r;                              \
        *(short*)((PW) + (TT)*8192 + prow*128                                  \
                  + (((jl>>3) ^ (prow&7))<<4) + (jl&7)*2)                      \
            = f2bf(fexp2(a_) * iD);                                            \
      }                                                                        \
    }                                                                          \
  }

#define PV_TILE(TT, PB, BF)                                                    \
  { _Pragma("unroll")                                                          \
    for (int m = 0; m < 4; ++m) {                                              \
      const int prow = m*16 + n16;                                             \
      short8 pa0 = *(const short8*)((PB) + (TT)*8192 + prow*128                \
                                    + (((0*4+g) ^ (prow&7))<<4));              \
      short8 pa1 = *(const short8*)((PB) + (TT)*8192 + prow*128                \
                                    + (((1*4+g) ^ (prow&7))<<4));              \
      _Pragma("unroll")                                                        \
      for (int nn = 0; nn < 2; ++nn) {                                         \
        acc[m][nn] = MFMA32(pa0, (BF)[nn*2+0], acc[m][nn]);                    \
        acc[m][nn] = MFMA32(pa1, (BF)[nn*2+1], acc[m][nn]);                    \
      }                                                                        \
    } }

#define LOAD_BF(DST, TILE)                                                     \
  { const short* sb_ = sct2 + ((size_t)(b*64 + (TILE))*8)*2048                 \
                            + (size_t)(w*32 + n16)*8;                          \
    _Pragma("unroll")                                                          \
    for (int nn = 0; nn < 2; ++nn)                                             \
      _Pragma("unroll")                                                        \
      for (int kc = 0; kc < 2; ++kc)                                           \
        (DST)[nn*2+kc] = *(const short8*)(sb_ + (size_t)(kc*4+g)*2048 + nn*128); }

#define WIN(W, q0C,t0C,d0C, q1C,t1C,d1C, bf0C,bf1C,                            \
            q0N,t0N,d0N, q1N,t1N,d1N, bf0N,bf1N)                               \
  {                                                                            \
    const int k0n = (2*(W)+2 < 64) ? 2*(W)+2 : 63;                             \
    const int k1n = (2*(W)+3 < 64) ? 2*(W)+3 : 63;                             \
    q0N = sqn[bbase + (size_t)k0n*64 + jl];                                    \
    t0N = T  [bbase + (size_t)k0n*64 + jl];                                    \
    d0N = D  [bbase + (size_t)k0n*64 + jl];                                    \
    q1N = sqn[bbase + (size_t)k1n*64 + jl];                                    \
    t1N = T  [bbase + (size_t)k1n*64 + jl];                                    \
    d1N = D  [bbase + (size_t)k1n*64 + jl];                                    \
    LOAD_BF(bf0N, k0n)                                                         \
    LOAD_BF(bf1N, k1n)                                                         \
    const char* Eb = (const char*)ejlds[(W)&1];                                \
    char* Pw = (char*)Plds[(W)&1];                                             \
    SCORE_XF(0, Eb, Pw, q0C, t0C, d0C)                                         \
    SCORE_XF(1, Eb, Pw, q1C, t1C, d1C)                                         \
    { char* En = (char*)ejlds[((W)+1)&1];                                      \
      *(short8*)(En + sbyte) = stgA;                                           \
      *(short8*)(En + 8192 + sbyte) = stgB;                                    \
      const int k0s = (2*(W)+4 < 64) ? 2*(W)+4 : 63;                           \
      const int k1s = (2*(W)+5 < 64) ? 2*(W)+5 : 63;                           \
      stgA = *(const short8*)(emb + (bbase + (size_t)k0s*64 + srow)*FC + sc8*8); \
      stgB = *(const short8*)(emb + (bbase + (size_t)k1s*64 + srow)*FC + sc8*8); \
    }                                                                          \
    __syncthreads();                                                           \
    const char* Pb = (const char*)Plds[(W)&1];                                 \
    __builtin_amdgcn_s_setprio(1);                                             \
    PV_TILE(0, Pb, bf0C)                                                       \
    PV_TILE(1, Pb, bf1C)                                                       \
    __builtin_amdgcn_s_setprio(0);                                             \
  }

__global__ __launch_bounds__(512, 2) void k_attn(const float* __restrict__ fm,
    const short* __restrict__ emb, const float* __restrict__ sqn,
    const float* __restrict__ T, const float* __restrict__ D,
    const short* __restrict__ sct2, float* __restrict__ out)
{
    const int bid = ((blockIdx.x & 7) << 5) | (blockIdx.x >> 3);  // 256 blocks
    const int b = bid >> 6;
    const int i0 = (bid & 63) * 64;
    const int t = threadIdx.x, w = t >> 6, lane = t & 63, g = lane >> 4, n16 = lane & 15;
    const size_t bbase = (size_t)b * HW;
    const size_t ibase = bbase + i0;
    __shared__ short ejlds[2][2*64*64];
    __shared__ short Plds[2][2*64*64];

    const int ih = w & 1, jq = w >> 1;
    const int jl = jq*16 + n16;

    short8 aQ0[2], aQ1[2];
    float snL[2][4];
    #pragma unroll
    for (int t2 = 0; t2 < 2; ++t2) {
        const size_t qr = ibase + ih*32 + t2*16 + n16;
        aQ0[t2] = *(const short8*)(emb + qr*FC + g*8);
        aQ1[t2] = *(const short8*)(emb + qr*FC + 32 + g*8);
        #pragma unroll
        for (int r = 0; r < 4; ++r)
            snL[t2][r] = -L2E * sqn[ibase + ih*32 + t2*16 + g*4 + r];
    }
    const int srow = t >> 3, sc8 = t & 7;
    const int sbyte = srow*128 + ((sc8*16) ^ ((srow&7)<<4));

    short8 stgA = *(const short8*)(emb + (bbase + srow)*FC + sc8*8);
    short8 stgB = *(const short8*)(emb + (bbase + 64 + srow)*FC + sc8*8);
    *(short8*)((char*)ejlds[0] + sbyte) = stgA;
    *(short8*)((char*)ejlds[0] + 8192 + sbyte) = stgB;
    stgA = *(const short8*)(emb + (bbase + 128 + srow)*FC + sc8*8);
    stgB = *(const short8*)(emb + (bbase + 192 + srow)*FC + sc8*8);
    float q0A = sqn[bbase + jl],      t0A = T[bbase + jl],      d0A = D[bbase + jl];
    float q1A = sqn[bbase + 64 + jl], t1A = T[bbase + 64 + jl], d1A = D[bbase + 64 + jl];
    float q0B, t0B, d0B, q1B, t1B, d1B;
    short8 bf0A[4], bf1A[4], bf0B[4], bf1B[4];
    LOAD_BF(bf0A, 0)
    LOAD_BF(bf1A, 1)
    f32x4 acc[4][2];
    #pragma unroll
    for (int m = 0; m < 4; ++m) {
        acc[m][0] = (f32x4){0.f,0.f,0.f,0.f};
        acc[m][1] = (f32x4){0.f,0.f,0.f,0.f};
    }
    __syncthreads();

    for (int w2 = 0; w2 < 32; w2 += 2) {
        WIN(w2,   q0A,t0A,d0A, q1A,t1A,d1A, bf0A,bf1A,
                  q0B,t0B,d0B, q1B,t1B,d1B, bf0B,bf1B)
        WIN(w2+1, q0B,t0B,d0B, q1B,t1B,d1B, bf0B,bf1B,
                  q0A,t0A,d0A, q1A,t1A,d1A, bf0A,bf1A)
    }

    #pragma unroll
    for (int m = 0; m < 4; ++m)
        #pragma unroll
        for (int r = 0; r < 4; ++r) {
            const size_t row = ibase + m*16 + g*4 + r;
            #pragma unroll
            for (int nn = 0; nn < 2; ++nn) {
                const size_t idx = row*CC + w*32 + nn*16 + n16;
                out[idx] = fm[idx] + acc[m][nn][r];
            }
        }
}

extern "C" void kernel_launch(void* const* d_in, const int* in_sizes, int n_in,
                              void* d_out, int out_size, void* d_ws, size_t ws_size,
                              hipStream_t stream)
{
    const float* fm   = (const float*)d_in[0];
    const float* Wemb = (const float*)d_in[1];
    const float* bemb = (const float*)d_in[2];
    const float* Watt = (const float*)d_in[3];
    const float* batt = (const float*)d_in[4];
    const float* Wthr = (const float*)d_in[5];
    const float* bthr = (const float*)d_in[6];
    char* ws = (char*)d_ws;
    short* emb   = (short*)(ws + OFF_EMB);
    short* sct2  = (short*)(ws + OFF_SCT2);
    float* sqn   = (float*)(ws + OFF_SQN);
    float* T     = (float*)(ws + OFF_T);
    float* D     = (float*)(ws + OFF_D);
    short* Wemb2 = (short*)(ws + OFF_WEMB2);
    short* Watt2 = (short*)(ws + OFF_WATT2);
    short* expA  = (short*)(ws + OFF_EXPA);
    float* out = (float*)d_out;

    k_prep  <<<320,  256, 0, stream>>>(Wemb, Watt, Wemb2, Watt2, D);
    k_front <<<1024, 256, 0, stream>>>(fm, Wemb2, Watt2, bemb, batt, Wthr, bthr,
                                       emb, sct2, sqn, T);
    if (ws_size >= WS_NEED) {
        k_colsum_w<<<2048, 256, 0, stream>>>(emb, sqn, T, D, expA);
        k_scale   <<<2048, 256, 0, stream>>>(sct2, D);
        k_attn_g  <<<512,  256, 0, stream>>>(fm, expA, sct2, out);
    } else {
        k_colsum<<<2048, 256, 0, stream>>>(emb, sqn, T, D);
        k_attn  <<<256,  512, 0, stream>>>(fm, emb, sqn, T, D, sct2, out);
    }
}

// Round 11
// 108.489 us; speedup vs baseline: 1.4474x; 1.4474x over previous
//
#include <hip/hip_runtime.h>
#include <hip/hip_bf16.h>
#include <math.h>

typedef __attribute__((ext_vector_type(8))) short short8;
typedef __attribute__((ext_vector_type(4))) short s16x4;
typedef __attribute__((ext_vector_type(4))) float f32x4;

#define BB 4
#define HW 4096
#define CC 256
#define FC 64
#define L2E 1.4426950408889634f

// ws byte offsets
#define OFF_EMB   0                      // short[16384*64]   = 2 MB
#define OFF_SCT2  (2*1024*1024)          // short[4*64*8*256*8] = 8 MB
#define OFF_SQN   (OFF_SCT2 + 8*1024*1024)
#define OFF_T     (OFF_SQN + 65536)
#define OFF_D     (OFF_T   + 65536)
#define OFF_WEMB2 (OFF_D   + 65536)      // short[32*64*8] = 32 KB
#define OFF_WATT2 (OFF_WEMB2 + 32768)    // short[32*256*8] = 128 KB
#define OFF_EXPA  (16*1024*1024)         // bf16 tiled [4][256][64][1024] = 128 MB
#define EXPA_BYTES ((size_t)BB*HW*HW*2)
#define WS_NEED   ((size_t)OFF_EXPA + EXPA_BYTES)

static __device__ __forceinline__ short f2bf(float f) {
    __hip_bfloat16 h = __float2bfloat16(f);
    return *reinterpret_cast<short*>(&h);
}
static __device__ __forceinline__ float bf2f(short s) {
    __hip_bfloat16 h = *reinterpret_cast<__hip_bfloat16*>(&s);
    return __bfloat162float(h);
}
static __device__ __forceinline__ float fexp2(float x) {
#if __has_builtin(__builtin_amdgcn_exp2f)
    return __builtin_amdgcn_exp2f(x);
#else
    float r; asm("v_exp_f32 %0, %1" : "=v"(r) : "v"(x)); return r;
#endif
}
static __device__ __forceinline__ float frcp(float x) {
#if __has_builtin(__builtin_amdgcn_rcpf)
    return __builtin_amdgcn_rcpf(x);
#else
    return 1.0f / x;
#endif
}
#define MFMA32(a, b, c) __builtin_amdgcn_mfma_f32_16x16x32_bf16(a, b, c, 0, 0, 0)

// ---------------------------------------------------------------------------
// K0: weight conversion to tiled bf16 B-fragment layouts + D zero.
// ---------------------------------------------------------------------------
__global__ __launch_bounds__(256) void k_prep(const float* __restrict__ Wemb,
    const float* __restrict__ Watt, short* __restrict__ Wemb2,
    short* __restrict__ Watt2, float* __restrict__ D)
{
    const int bid = blockIdx.x, t = threadIdx.x;
    if (bid < 256) {
        Watt2[(size_t)(t>>3)*2048 + bid*8 + (t&7)] = f2bf(Watt[(size_t)bid*256 + t]);
        if (bid < 64) D[bid*256 + t] = 0.f;
    } else {
        const int f = bid - 256;
        Wemb2[(size_t)(t>>3)*512 + f*8 + (t&7)] = f2bf(Wemb[(size_t)f*256 + t]);
    }
}

// ---------------------------------------------------------------------------
// K1 (fused emb + shortcut + threshold, all MFMA). grid 1024 x 256.
// ---------------------------------------------------------------------------
__global__ __launch_bounds__(256) void k_front(const float* __restrict__ fm,
    const short* __restrict__ Wemb2, const short* __restrict__ Watt2,
    const float* __restrict__ bemb, const float* __restrict__ batt,
    const float* __restrict__ wthr, const float* __restrict__ bthr,
    short* __restrict__ emb, short* __restrict__ sct2,
    float* __restrict__ sqn, float* __restrict__ T)
{
    const int blk = blockIdx.x;
    const int b = blk >> 8;
    const int r0 = (blk & 255) * 16;
    const int t = threadIdx.x;
    const int w = t >> 6, lane = t & 63, g = lane >> 4, n16 = lane & 15;
    __shared__ short fmt[16*256];
    __shared__ float tred[16][4];
    __shared__ float qred[16][4];
    #pragma unroll
    for (int v = t; v < 512; v += 256) {
        const int row = v >> 5, c32 = v & 31;
        const float4* src = (const float4*)(fm + ((size_t)b*HW + r0 + row)*CC + c32*8);
        float4 x0 = src[0], x1 = src[1];
        short8 pv;
        pv[0]=f2bf(x0.x); pv[1]=f2bf(x0.y); pv[2]=f2bf(x0.z); pv[3]=f2bf(x0.w);
        pv[4]=f2bf(x1.x); pv[5]=f2bf(x1.y); pv[6]=f2bf(x1.z); pv[7]=f2bf(x1.w);
        *(short8*)((char*)fmt + row*512 + ((c32*16) ^ ((row&7)<<4))) = pv;
    }
    __syncthreads();
    const int cb = w*64, fb = w*16;
    f32x4 acc[4], acce;
    #pragma unroll
    for (int nn = 0; nn < 4; ++nn) acc[nn] = (f32x4){0.f,0.f,0.f,0.f};
    acce = (f32x4){0.f,0.f,0.f,0.f};
    #pragma unroll
    for (int kk = 0; kk < 8; ++kk) {
        const int kc = kk*4 + g;
        short8 a = *(const short8*)((const char*)fmt + n16*512 + ((kc*16) ^ ((n16&7)<<4)));
        const short* wb = Watt2 + (size_t)kc*2048 + (cb + n16)*8;
        #pragma unroll
        for (int nn = 0; nn < 4; ++nn) {
            short8 bv = *(const short8*)(wb + nn*128);
            acc[nn] = MFMA32(a, bv, acc[nn]);
        }
        short8 be = *(const short8*)(Wemb2 + (size_t)kc*512 + (fb + n16)*8);
        acce = MFMA32(a, be, acce);
    }
    float tp[4] = {0.f,0.f,0.f,0.f};
    const int jt_ = r0 >> 6;
    const int jc0 = (r0 & 63) >> 3;
    const size_t tilebase = ((size_t)b*64 + jt_)*8;
    #pragma unroll
    for (int nn = 0; nn < 4; ++nn) {
        const int ch = cb + nn*16 + n16;
        const float ba_ = batt[ch], wt_ = wthr[ch];
        float v[4];
        #pragma unroll
        for (int r = 0; r < 4; ++r) { v[r] = acc[nn][r] + ba_; tp[r] = fmaf(v[r], wt_, tp[r]); }
        const int jc = jc0 + (g >> 1);
        const int jw0 = (g & 1)*4;
        short* dstp = sct2 + (tilebase + jc)*2048 + (size_t)ch*8;
        unsigned u01 = (unsigned short)f2bf(v[0]) | ((unsigned)(unsigned short)f2bf(v[1]) << 16);
        unsigned u23 = (unsigned short)f2bf(v[2]) | ((unsigned)(unsigned short)f2bf(v[3]) << 16);
        *(unsigned*)(dstp + jw0)     = u01;
        *(unsigned*)(dstp + jw0 + 2) = u23;
    }
    #pragma unroll
    for (int r = 0; r < 4; ++r)
        #pragma unroll
        for (int off = 1; off <= 8; off <<= 1) tp[r] += __shfl_xor(tp[r], off);
    const int f = fb + n16;
    const float be_ = bemb[f];
    float qp[4];
    #pragma unroll
    for (int r = 0; r < 4; ++r) {
        short bv = f2bf(acce[r] + be_);
        emb[((size_t)b*HW + r0 + g*4 + r)*FC + f] = bv;
        float ef = bf2f(bv);
        qp[r] = ef*ef;
        #pragma unroll
        for (int off = 1; off <= 8; off <<= 1) qp[r] += __shfl_xor(qp[r], off);
    }
    if (n16 == 0) {
        #pragma unroll
        for (int r = 0; r < 4; ++r) { tred[g*4+r][w] = tp[r]; qred[g*4+r][w] = qp[r]; }
    }
    __syncthreads();
    if (t < 16) {
        T[(size_t)b*HW + r0 + t]   = tred[t][0]+tred[t][1]+tred[t][2]+tred[t][3] + bthr[0];
        sqn[(size_t)b*HW + r0 + t] = qred[t][0]+qred[t][1]+qred[t][2]+qred[t][3];
    }
}

// ---------------------------------------------------------------------------
// K2w: column sums D[j] + write unnormalized expA, TILED layout:
// expA[((b*256+itile)*64+jt)*1024 + w*256 + g*64 + n16*4 + r]  (coalesced).
// tile = 16 i x 64 j (2 KB). grid 2048 x 256.
// ---------------------------------------------------------------------------
__global__ __launch_bounds__(256) void k_colsum_w(const short* __restrict__ emb,
    const float* __restrict__ sqn, const float* __restrict__ T,
    float* __restrict__ D, short* __restrict__ expA)
{
    const int bid = blockIdx.x;
    const int split = bid & 7, jt = (bid >> 3) & 63, b = bid >> 9;
    const int t = threadIdx.x, w = t >> 6, lane = t & 63, g = lane >> 4, n16 = lane & 15;
    const size_t jbase = (size_t)b*HW + jt*64;
    __shared__ short ej[64*64];
    __shared__ short ei[2][64*64];
    __shared__ float sqni[2][64];
    #pragma unroll
    for (int v = t; v < 512; v += 256) {
        const int row = v >> 3, c8 = v & 7;
        short8 x = *(const short8*)(emb + (jbase + row)*FC + c8*8);
        *(short8*)((char*)ej + row*128 + ((c8*16) ^ ((row&7)<<4))) = x;
    }
    const int jl = w*16 + n16;
    f32x4 sqjL, tjL;
    {
        f32x4 q = *(const f32x4*)(sqn + jbase + w*16 + g*4);
        f32x4 tt = *(const f32x4*)(T + jbase + w*16 + g*4);
        #pragma unroll
        for (int r = 0; r < 4; ++r) { sqjL[r] = -L2E*q[r]; tjL[r] = -L2E*tt[r]; }
    }
    const int srow0 = t >> 3, srow1 = (t >> 3) + 32, sc8 = t & 7;
    const int sb0 = srow0*128 + ((sc8*16) ^ ((srow0&7)<<4));
    const int sb1 = srow1*128 + ((sc8*16) ^ ((srow1&7)<<4));
    const size_t base0 = (size_t)b*HW + (size_t)split*512;
    short8 stg0 = *(const short8*)(emb + (base0 + srow0)*FC + sc8*8);
    short8 stg1 = *(const short8*)(emb + (base0 + srow1)*FC + sc8*8);
    float stgq = (t < 64) ? sqn[base0 + t] : 0.f;
    *(short8*)((char*)ei[0] + sb0) = stg0;
    *(short8*)((char*)ei[0] + sb1) = stg1;
    if (t < 64) sqni[0][t] = stgq;
    stg0 = *(const short8*)(emb + (base0 + 64 + srow0)*FC + sc8*8);
    stg1 = *(const short8*)(emb + (base0 + 64 + srow1)*FC + sc8*8);
    stgq = (t < 64) ? sqn[base0 + 64 + t] : 0.f;
    __syncthreads();
    const short8 bf0 = *(const short8*)((const char*)ej + jl*128 + ((g*16)     ^ ((jl&7)<<4)));
    const short8 bf1 = *(const short8*)((const char*)ej + jl*128 + (((g+4)*16) ^ ((jl&7)<<4)));
    f32x4 csum = {0.f,0.f,0.f,0.f};
    const int woff = w*256 + g*64 + n16*4;
    for (int it = 0; it < 8; ++it) {
        if (it < 7) {
            char* eib = (char*)ei[(it+1)&1];
            *(short8*)(eib + sb0) = stg0;
            *(short8*)(eib + sb1) = stg1;
            if (t < 64) sqni[(it+1)&1][t] = stgq;
            if (it < 6) {
                const size_t nb = base0 + (size_t)(it+2)*64;
                stg0 = *(const short8*)(emb + (nb + srow0)*FC + sc8*8);
                stg1 = *(const short8*)(emb + (nb + srow1)*FC + sc8*8);
                stgq = (t < 64) ? sqn[nb + t] : 0.f;
            }
        }
        const char* eib = (const char*)ei[it&1];
        const float* sqc = sqni[it&1];
        #pragma unroll
        for (int m = 0; m < 4; ++m) {
            const int arow = m*16 + n16;
            short8 a0 = *(const short8*)(eib + arow*128 + ((g*16)     ^ ((arow&7)<<4)));
            short8 a1 = *(const short8*)(eib + arow*128 + (((g+4)*16) ^ ((arow&7)<<4)));
            f32x4 dot = {0.f,0.f,0.f,0.f};
            dot = MFMA32(bf0, a0, dot);   // swapped: lane col = i = n16
            dot = MFMA32(bf1, a1, dot);
            const float sniL = -L2E * sqc[m*16 + n16];
            s16x4 pk;
            #pragma unroll
            for (int r = 0; r < 4; ++r) {
                float x1 = fminf(fmaf(dot[r], 2.f*L2E, sniL + sqjL[r]), 0.f);
                float a_ = fmaxf(fmaf(fexp2(x1), L2E, tjL[r]), 0.f);
                float val = fexp2(a_);
                csum[r] += val;
                pk[r] = f2bf(val);
            }
            const int itile = split*32 + it*4 + m;
            *(s16x4*)(expA + ((((size_t)b*256 + itile)*64 + jt) << 10) + woff) = pk;
        }
        __syncthreads();
    }
    #pragma unroll
    for (int r = 0; r < 4; ++r) {
        csum[r] += __shfl_xor(csum[r], 1);
        csum[r] += __shfl_xor(csum[r], 2);
        csum[r] += __shfl_xor(csum[r], 4);
        csum[r] += __shfl_xor(csum[r], 8);
    }
    if (n16 == 0) {
        #pragma unroll
        for (int r = 0; r < 4; ++r) atomicAdd(&D[jbase + w*16 + g*4 + r], csum[r]);
    }
}

// ---------------------------------------------------------------------------
// K3s: fold 1/D[j] into sct2 (in place). grid 2048 x 256.
// ---------------------------------------------------------------------------
__global__ __launch_bounds__(256) void k_scale(short* __restrict__ sct2,
    const float* __restrict__ D)
{
    const int v = blockIdx.x*256 + threadIdx.x;
    const int ch = v & 255, jc = (v >> 8) & 7, jt = (v >> 11) & 63, b = v >> 17;
    const size_t jb = (size_t)b*HW + jt*64 + jc*8;
    f32x4 d0 = *(const f32x4*)(D + jb);
    f32x4 d1 = *(const f32x4*)(D + jb + 4);
    short8* p = (short8*)(sct2 + ((((size_t)b*64 + jt)*8 + jc)*256 + ch)*8);
    short8 x = *p;
    short8 y;
    y[0] = f2bf(bf2f(x[0]) * frcp(d0[0]));
    y[1] = f2bf(bf2f(x[1]) * frcp(d0[1]));
    y[2] = f2bf(bf2f(x[2]) * frcp(d0[2]));
    y[3] = f2bf(bf2f(x[3]) * frcp(d0[3]));
    y[4] = f2bf(bf2f(x[4]) * frcp(d1[0]));
    y[5] = f2bf(bf2f(x[5]) * frcp(d1[1]));
    y[6] = f2bf(bf2f(x[6]) * frcp(d1[2]));
    y[7] = f2bf(bf2f(x[7]) * frcp(d1[3]));
    *p = y;
}

// ---------------------------------------------------------------------------
// K4g: pure GEMM out = fm + expA @ sc'. grid 256 x 512 (8 waves), 64 rows.
// A-tile (8KB/jt) reg-staged 2 windows ahead -> LDS dbuf; B reg-prefetched
// 1 ahead from L2. 1 barrier/jt. wave w: channels w*32..+31 x all 64 rows.
// ---------------------------------------------------------------------------
#define LDB2(DST, JT) { const short* q_ = Bbase + (size_t)(JT)*16384;          \
        _Pragma("unroll") for (int nn = 0; nn < 2; ++nn)                       \
        _Pragma("unroll") for (int kc = 0; kc < 2; ++kc)                       \
        (DST)[nn*2+kc] = *(const short8*)(q_ + (kc*4+g)*2048 + nn*128); }

#define GTILE2(AB, BF) { _Pragma("unroll") for (int m = 0; m < 4; ++m) {       \
        s16x4 q0 = *(const s16x4*)((AB) + m*2048 + fo0);                       \
        s16x4 q1 = *(const s16x4*)((AB) + m*2048 + fo0 + 128);                 \
        s16x4 q2 = *(const s16x4*)((AB) + m*2048 + fo1);                       \
        s16x4 q3 = *(const s16x4*)((AB) + m*2048 + fo1 + 128);                 \
        short8 a0 = __builtin_shufflevector(q0, q1, 0,1,2,3,4,5,6,7);          \
        short8 a1 = __builtin_shufflevector(q2, q3, 0,1,2,3,4,5,6,7);          \
        _Pragma("unroll") for (int nn = 0; nn < 2; ++nn) {                     \
            acc[m][nn] = MFMA32(a0, (BF)[nn*2+0], acc[m][nn]);                 \
            acc[m][nn] = MFMA32(a1, (BF)[nn*2+1], acc[m][nn]);                 \
        } } }

__global__ __launch_bounds__(512, 2) void k_attn_g(const float* __restrict__ fm,
    const short* __restrict__ expA, const short* __restrict__ sct2,
    float* __restrict__ out)
{
    const int bid = ((blockIdx.x & 7) << 5) | (blockIdx.x >> 3);  // 256 blocks
    const int b = bid >> 6;
    const int i0 = (bid & 63) * 64;
    const int t = threadIdx.x, w = t >> 6, lane = t & 63, g = lane >> 4, n16 = lane & 15;
    __shared__ short ALDS[2][4096];   // 2 x 8KB

    // staging: thread t covers itile (t>>7), 16B chunk (t&127) of each jt-slab
    const short* stgbase = expA + ((size_t)(b*256 + (bid & 63)*4 + (t>>7)) << 16)
                                + (size_t)(t & 127)*8;
    short* sdst = &ALDS[0][0] + t*8;           // [buf][t*8] shorts (16B/thread)
    const int sstride = 4096;                  // shorts per buf

    // fragment read offsets (bytes within tile): q0/q1 = kc0, q2/q3 = kc1
    const int fo0 = (g>>1)*512 + (g&1)*256 + n16*8;
    const int fo1 = 1024 + fo0;

    const short* Bbase = sct2 + (size_t)(b*64)*8*2048 + (size_t)(w*32 + n16)*8;

    f32x4 acc[4][2];
    #pragma unroll
    for (int m = 0; m < 4; ++m) {
        acc[m][0] = (f32x4){0.f,0.f,0.f,0.f};
        acc[m][1] = (f32x4){0.f,0.f,0.f,0.f};
    }

    short8 bfA[4], bfB[4];
    LDB2(bfA, 0)
    // prologue: tile0 -> buf0; stgB holds tile1
    short8 tmp = *(const short8*)(stgbase);           // jt=0
    *(short8*)(sdst) = tmp;
    short8 stgA, stgB = *(const short8*)(stgbase + 1024);  // jt=1
    __syncthreads();   // buf0 ready

    #pragma unroll 2
    for (int jt = 0; jt < 64; ++jt) {
        const int even = !(jt & 1);
        // issue A load 2 tiles ahead
        if (jt < 62) {
            if (even) stgA = *(const short8*)(stgbase + (size_t)(jt+2)*1024);
            else      stgB = *(const short8*)(stgbase + (size_t)(jt+2)*1024);
        }
        // B prefetch 1 tile ahead
        if (jt < 63) { if (even) { LDB2(bfB, jt+1) } else { LDB2(bfA, jt+1) } }
        // compute current tile
        const char* Ab = (const char*)&ALDS[jt & 1][0];
        __builtin_amdgcn_s_setprio(1);
        if (even) { GTILE2(Ab, bfA) } else { GTILE2(Ab, bfB) }
        __builtin_amdgcn_s_setprio(0);
        // write pending A (tile jt+1) into the other buffer
        if (jt < 63) {
            short* d = &ALDS[(jt+1) & 1][0] + t*8;
            *(short8*)d = even ? stgB : stgA;
        }
        __syncthreads();
    }

    const size_t ibase = (size_t)b*HW + i0;
    #pragma unroll
    for (int m = 0; m < 4; ++m)
        #pragma unroll
        for (int r = 0; r < 4; ++r) {
            const size_t row = ibase + m*16 + g*4 + r;
            #pragma unroll
            for (int nn = 0; nn < 2; ++nn) {
                const size_t idx = row*CC + w*32 + nn*16 + n16;
                out[idx] = fm[idx] + acc[m][nn][r];
            }
        }
}

// ---------------------------------------------------------------------------
// Fallback path (ws too small): R4-style fused attn + plain colsum.
// ---------------------------------------------------------------------------
__global__ __launch_bounds__(256) void k_colsum(const short* __restrict__ emb,
    const float* __restrict__ sqn, const float* __restrict__ T,
    float* __restrict__ D)
{
    const int bid = blockIdx.x;
    const int split = bid & 7, jt = (bid >> 3) & 63, b = bid >> 9;
    const int t = threadIdx.x, w = t >> 6, lane = t & 63, g = lane >> 4, n16 = lane & 15;
    const size_t jbase = (size_t)b*HW + jt*64;
    __shared__ short ej[64*64];
    __shared__ short ei[64*64];
    __shared__ float sqni[64];
    #pragma unroll
    for (int v = t; v < 512; v += 256) {
        const int row = v >> 3, c8 = v & 7;
        short8 x = *(const short8*)(emb + (jbase + row)*FC + c8*8);
        *(short8*)((char*)ej + row*128 + ((c8*16) ^ ((row&7)<<4))) = x;
    }
    const int jl = w*16 + n16;
    const float sqjL = -L2E * sqn[jbase + jl];
    const float tjL  = -L2E * T[jbase + jl];
    __syncthreads();
    const short8 bf0 = *(const short8*)((const char*)ej + jl*128 + ((g*16)     ^ ((jl&7)<<4)));
    const short8 bf1 = *(const short8*)((const char*)ej + jl*128 + (((g+4)*16) ^ ((jl&7)<<4)));
    float csum = 0.f;
    for (int it = 0; it < 8; ++it) {
        const size_t ibase2 = (size_t)b*HW + (size_t)(split*8 + it)*64;
        __syncthreads();
        #pragma unroll
        for (int v = t; v < 512; v += 256) {
            const int row = v >> 3, c8 = v & 7;
            short8 x = *(const short8*)(emb + (ibase2 + row)*FC + c8*8);
            *(short8*)((char*)ei + row*128 + ((c8*16) ^ ((row&7)<<4))) = x;
        }
        if (t < 64) sqni[t] = sqn[ibase2 + t];
        __syncthreads();
        #pragma unroll
        for (int m = 0; m < 4; ++m) {
            const int arow = m*16 + n16;
            short8 a0 = *(const short8*)((const char*)ei + arow*128 + ((g*16)     ^ ((arow&7)<<4)));
            short8 a1 = *(const short8*)((const char*)ei + arow*128 + (((g+4)*16) ^ ((arow&7)<<4)));
            f32x4 dot = {0.f,0.f,0.f,0.f};
            dot = MFMA32(a0, bf0, dot);
            dot = MFMA32(a1, bf1, dot);
            #pragma unroll
            for (int r = 0; r < 4; ++r) {
                float x1 = fminf(fmaf(dot[r], 2.f*L2E, fmaf(-L2E, sqni[m*16 + g*4 + r], sqjL)), 0.f);
                float e1 = fexp2(x1);
                float a_ = fmaxf(fmaf(e1, L2E, tjL), 0.f);
                csum += fexp2(a_);
            }
        }
    }
    csum += __shfl_xor(csum, 16);
    csum += __shfl_xor(csum, 32);
    if (lane < 16) atomicAdd(&D[jbase + jl], csum);
}

__global__ __launch_bounds__(256, 2) void k_attn_f(const float* __restrict__ fm,
    const short* __restrict__ emb, const float* __restrict__ sqn,
    const float* __restrict__ T, const float* __restrict__ D,
    const short* __restrict__ sct2, float* __restrict__ out)
{
    const int bid = ((blockIdx.x & 7) << 6) | (blockIdx.x >> 3);
    const int b = bid >> 7;
    const int i0 = (bid & 127) * 32;
    const int t = threadIdx.x, w = t >> 6, lane = t & 63, g = lane >> 4, n16 = lane & 15;
    const size_t bbase = (size_t)b * HW;
    const size_t ibase = bbase + i0;
    __shared__ short ejlds[64*64];
    __shared__ short Plds[32*64];
    const int jl = w*16 + n16;
    short8 aQ0[2], aQ1[2];
    float snL[2][4];
    #pragma unroll
    for (int t2 = 0; t2 < 2; ++t2) {
        const size_t qr = ibase + t2*16 + n16;
        aQ0[t2] = *(const short8*)(emb + qr*FC + g*8);
        aQ1[t2] = *(const short8*)(emb + qr*FC + 32 + g*8);
        #pragma unroll
        for (int r = 0; r < 4; ++r)
            snL[t2][r] = -L2E * sqn[ibase + t2*16 + g*4 + r];
    }
    const int srow0 = t >> 3, srow1 = (t >> 3) + 32, sc8 = t & 7;
    const int sbyte0 = srow0*128 + ((sc8*16) ^ ((srow0&7)<<4));
    const int sbyte1 = srow1*128 + ((sc8*16) ^ ((srow1&7)<<4));
    f32x4 acc[2][4];
    #pragma unroll
    for (int m = 0; m < 2; ++m)
        #pragma unroll
        for (int nn = 0; nn < 4; ++nn) acc[m][nn] = (f32x4){0.f,0.f,0.f,0.f};
    for (int jt = 0; jt < 64; ++jt) {
        const size_t jbase = bbase + (size_t)jt*64;
        __syncthreads();
        *(short8*)((char*)ejlds + sbyte0) = *(const short8*)(emb + (jbase + srow0)*FC + sc8*8);
        *(short8*)((char*)ejlds + sbyte1) = *(const short8*)(emb + (jbase + srow1)*FC + sc8*8);
        const float sqjL = -L2E * sqn[jbase + jl];
        const float tjL  = -L2E * T[jbase + jl];
        const float iD   = frcp(D[jbase + jl]);
        __syncthreads();
        short8 b0 = *(const short8*)((const char*)ejlds + jl*128 + ((g*16)     ^ ((jl&7)<<4)));
        short8 b1 = *(const short8*)((const char*)ejlds + jl*128 + (((g+4)*16) ^ ((jl&7)<<4)));
        #pragma unroll
        for (int t2 = 0; t2 < 2; ++t2) {
            f32x4 dot = {0.f,0.f,0.f,0.f};
            dot = MFMA32(aQ0[t2], b0, dot);
            dot = MFMA32(aQ1[t2], b1, dot);
            #pragma unroll
            for (int r = 0; r < 4; ++r) {
                float x1 = fminf(fmaf(dot[r], 2.f*L2E, snL[t2][r] + sqjL), 0.f);
                float a_ = fmaxf(fmaf(fexp2(x1), L2E, tjL), 0.f);
                const int prow = t2*16 + g*4 + r;
                *(short*)((char*)Plds + prow*128 + (((jl>>3) ^ (prow&7))<<4) + (jl&7)*2)
                    = f2bf(fexp2(a_) * iD);
            }
        }
        __syncthreads();
        const short* sb = sct2 + ((size_t)(b*64 + jt)*8)*2048 + (size_t)(w*64 + n16)*8;
        #pragma unroll
        for (int m = 0; m < 2; ++m) {
            const int prow = m*16 + n16;
            short8 pa0 = *(const short8*)((const char*)Plds + prow*128 + (((0*4+g) ^ (prow&7))<<4));
            short8 pa1 = *(const short8*)((const char*)Plds + prow*128 + (((1*4+g) ^ (prow&7))<<4));
            #pragma unroll
            for (int nn = 0; nn < 4; ++nn) {
                short8 bv0 = *(const short8*)(sb + (size_t)(0*4+g)*2048 + nn*128);
                short8 bv1 = *(const short8*)(sb + (size_t)(1*4+g)*2048 + nn*128);
                acc[m][nn] = MFMA32(pa0, bv0, acc[m][nn]);
                acc[m][nn] = MFMA32(pa1, bv1, acc[m][nn]);
            }
        }
    }
    #pragma unroll
    for (int m = 0; m < 2; ++m)
        #pragma unroll
        for (int r = 0; r < 4; ++r) {
            const size_t row = ibase + m*16 + g*4 + r;
            #pragma unroll
            for (int nn = 0; nn < 4; ++nn) {
                const size_t idx = row*CC + w*64 + nn*16 + n16;
                out[idx] = fm[idx] + acc[m][nn][r];
            }
        }
}

extern "C" void kernel_launch(void* const* d_in, const int* in_sizes, int n_in,
                              void* d_out, int out_size, void* d_ws, size_t ws_size,
                              hipStream_t stream)
{
    const float* fm   = (const float*)d_in[0];
    const float* Wemb = (const float*)d_in[1];
    const float* bemb = (const float*)d_in[2];
    const float* Watt = (const float*)d_in[3];
    const float* batt = (const float*)d_in[4];
    const float* Wthr = (const float*)d_in[5];
    const float* bthr = (const float*)d_in[6];
    char* ws = (char*)d_ws;
    short* emb   = (short*)(ws + OFF_EMB);
    short* sct2  = (short*)(ws + OFF_SCT2);
    float* sqn   = (float*)(ws + OFF_SQN);
    float* T     = (float*)(ws + OFF_T);
    float* D     = (float*)(ws + OFF_D);
    short* Wemb2 = (short*)(ws + OFF_WEMB2);
    short* Watt2 = (short*)(ws + OFF_WATT2);
    short* expA  = (short*)(ws + OFF_EXPA);
    float* out = (float*)d_out;

    k_prep  <<<320,  256, 0, stream>>>(Wemb, Watt, Wemb2, Watt2, D);
    k_front <<<1024, 256, 0, stream>>>(fm, Wemb2, Watt2, bemb, batt, Wthr, bthr,
                                       emb, sct2, sqn, T);
    if (ws_size >= WS_NEED) {
        k_colsum_w<<<2048, 256, 0, stream>>>(emb, sqn, T, D, expA);
        k_scale   <<<2048, 256, 0, stream>>>(sct2, D);
        k_attn_g  <<<256,  512, 0, stream>>>(fm, expA, sct2, out);
    } else {
        k_colsum<<<2048, 256, 0, stream>>>(emb, sqn, T, D);
        k_attn_f<<<512,  256, 0, stream>>>(fm, emb, sqn, T, D, sct2, out);
    }
}